// Round 4
// baseline (76.675 us; speedup 1.0000x reference)
//
#include <hip/hip_runtime.h>
#include <hip/hip_bf16.h>

#define NB 4
#define NN 2048
#define NF 256
#define TSTEPS 16   // NN / 128

using bf16x8 = __attribute__((ext_vector_type(8))) short;
using f32x4  = __attribute__((ext_vector_type(4))) float;
using i32x4  = __attribute__((ext_vector_type(4))) int;

__device__ __forceinline__ short f2bf(float f) {
    unsigned u = __float_as_uint(f);
    u += 0x7fffu + ((u >> 16) & 1u);   // RNE, finite inputs only
    return (short)(u >> 16);
}
__device__ __forceinline__ unsigned enc_ord(float f) {   // order-preserving f32->u32
    unsigned u = __float_as_uint(f);
    return (u & 0x80000000u) ? ~u : (u | 0x80000000u);
}
__device__ __forceinline__ float dec_ord(unsigned u) {
    unsigned i = (u & 0x80000000u) ? (u & 0x7fffffffu) : ~u;
    return __uint_as_float(i);
}

// ---- prep: x->bf16 (grid-stride), W->W^T bf16, zero maxfd ----
__global__ __launch_bounds__(256) void prep_kernel(
    const float* __restrict__ x, const float* __restrict__ W,
    short* __restrict__ WT, short* __restrict__ xb, unsigned* __restrict__ maxfd)
{
    const int gid = blockIdx.x * 256 + threadIdx.x;     // grid 1024 -> 262144 threads
    for (int s = gid; s < (NB*NN*NF)/4; s += 262144) {
        float4 v = ((const float4*)x)[s];
        short4 o;
        o.x = f2bf(v.x); o.y = f2bf(v.y); o.z = f2bf(v.z); o.w = f2bf(v.w);
        ((short4*)xb)[s] = o;
    }
    if (gid < NF*NF) {
        int g = gid >> 8, f = gid & 255;
        WT[gid] = f2bf(W[f*NF + g]);        // WT[g][f] = W[f][g]
    }
    if (gid < NB) maxfd[gid] = 0u;
}

// ---- h = x@W (bf16 MFMA); hT[b][g][i] bf16, f_src/f_dst, per-batch max(fdst) ----
__global__ __launch_bounds__(256,4) void h_kernel(
    const short* __restrict__ xb, const short* __restrict__ WT, const float* __restrict__ a,
    short* __restrict__ hT, float* __restrict__ fsrc, float* __restrict__ fdst,
    unsigned* __restrict__ maxfd)
{
    __shared__ float fs_l[16], fd_l[16];
    const int w  = threadIdx.x >> 6;
    const int l  = threadIdx.x & 63;
    const int lr = l & 15, lg = l >> 4;
    const int b  = blockIdx.x >> 7;
    const int ib = (blockIdx.x & 127) * 16;

    if (threadIdx.x < 16) { fs_l[threadIdx.x] = 0.f; fd_l[threadIdx.x] = 0.f; }
    __syncthreads();

    f32x4 acc[4];
    #pragma unroll
    for (int t = 0; t < 4; t++) acc[t] = (f32x4){0.f,0.f,0.f,0.f};

    const short* xrow = xb + (size_t)(b*NN + ib + lr) * NF;
    #pragma unroll
    for (int k0 = 0; k0 < NF; k0 += 32) {
        bf16x8 af = *(const bf16x8*)(xrow + k0 + 8*lg);
        #pragma unroll
        for (int nt = 0; nt < 4; nt++) {
            int g = w*64 + nt*16 + lr;
            bf16x8 bf = *(const bf16x8*)(WT + (size_t)g*NF + k0 + 8*lg);
            acc[nt] = __builtin_amdgcn_mfma_f32_16x16x32_bf16(af, bf, acc[nt], 0, 0, 0);
        }
    }

    float fsv[4] = {0,0,0,0}, fdv[4] = {0,0,0,0};
    #pragma unroll
    for (int nt = 0; nt < 4; nt++) {
        int g = w*64 + nt*16 + lr;
        float as = a[g], ad = a[NF + g];
        short4 hv;
        hv.x = f2bf(acc[nt][0]); hv.y = f2bf(acc[nt][1]);
        hv.z = f2bf(acc[nt][2]); hv.w = f2bf(acc[nt][3]);
        *(short4*)(hT + ((size_t)(b*NF + g))*NN + ib + lg*4) = hv;
        #pragma unroll
        for (int r = 0; r < 4; r++) { fsv[r] += acc[nt][r]*as; fdv[r] += acc[nt][r]*ad; }
    }
    #pragma unroll
    for (int mask = 1; mask < 16; mask <<= 1) {
        #pragma unroll
        for (int r = 0; r < 4; r++) {
            fsv[r] += __shfl_xor(fsv[r], mask);
            fdv[r] += __shfl_xor(fdv[r], mask);
        }
    }
    if (lr == 0) {
        #pragma unroll
        for (int r = 0; r < 4; r++) {
            atomicAdd(&fs_l[lg*4 + r], fsv[r]);
            atomicAdd(&fd_l[lg*4 + r], fdv[r]);
        }
    }
    __syncthreads();
    if (threadIdx.x < 16) {
        float fsu = fs_l[threadIdx.x], fdu = fd_l[threadIdx.x];
        fsrc[b*NN + ib + threadIdx.x] = fsu;
        fdst[b*NN + ib + threadIdx.x] = fdu;
        float wm = fdu;
        #pragma unroll
        for (int m = 1; m < 16; m <<= 1) wm = fmaxf(wm, __shfl_xor(wm, m));
        if (threadIdx.x == 0) atomicMax(maxfd + b, enc_ord(wm));
    }
}

// ---- fused: masked softmax + att@h + elu ----
// grid 256 (1 block/CU), 1024 thr (16 waves = 4/SIMD). Block: 32 rows, BK=128, 16 steps.
// Waves: fq = w&3 (64 f-cols), kt = w>>2 (32-j slice of the 128 step) -> zero B redundancy.
// B-frags: per-wave L2-direct VGPR loads, double-buffered (counted vmcnt, no LDS).
// P-tile: 32x128 bf16 in LDS, 2 slots, XOR-swizzled; ONE raw s_barrier per step.
#define RED0_OFF 0
#define RED1_OFF 33280
#define P_OFF    66560
#define LS_OFF   82944
__global__ __launch_bounds__(1024,4) void gat_fused(
    const short* __restrict__ hT, const int* __restrict__ adj,
    const float* __restrict__ fsrc, const float* __restrict__ fdst,
    const unsigned* __restrict__ maxfd, float* __restrict__ out)
{
    __shared__ __align__(16) char smem[83072];
    float* ls = (float*)(smem + LS_OFF);

    const int tid = threadIdx.x;
    const int w = tid >> 6, l = tid & 63, lr = l & 15, lg = l >> 4;
    const int fq = w & 3, kt = w >> 2;
    const int blk = blockIdx.x, b = blk >> 6, i0 = (blk & 63) * 32;

    // P-thread coords: row prow, j-group pc (4 j's per thread per step)
    const int prow = tid >> 5, pc = tid & 31;
    const int pig = b*NN + i0 + prow;
    const float pfs = fsrc[pig];
    const float M = fmaxf(pfs + dec_ord(maxfd[b]), 0.f);   // >= row max, >= 0
    const int*   adjrow = adj + (size_t)pig * NN + pc*4;
    const float* fdb    = fdst + b*NN + pc*4;
    const short* hTb    = hT + (size_t)b * NF * NN;

    f32x4 acc[2][4];
    #pragma unroll
    for (int a1 = 0; a1 < 2; ++a1)
        #pragma unroll
        for (int a2 = 0; a2 < 4; ++a2) acc[a1][a2] = (f32x4){0.f,0.f,0.f,0.f};
    float lsum = 0.f;

    auto LOADA = [&](int step, i32x4& av, f32x4& fv) {
        av = __builtin_nontemporal_load((const i32x4*)(adjrow + step*NN*0 + (step << 7)));
        fv = *(const f32x4*)(fdb + (step << 7));
    };
    auto LOADB = [&](int step, bf16x8* bv) {
        const short* base = hTb + (size_t)(fq*64 + lr)*NN + (step << 7) + kt*32 + lg*8;
        #pragma unroll
        for (int nt = 0; nt < 4; ++nt)
            bv[nt] = *(const bf16x8*)(base + (size_t)nt*16*NN);
    };
    auto EXPP = [&](int t, const i32x4& av, const f32x4& fv) {
        float pv[4];
        #pragma unroll
        for (int e = 0; e < 4; ++e) {
            float ev = fmaxf(pfs + fv[e], 0.f);
            float pe = (av[e] > 0) ? __expf(ev - M) : 0.f;
            lsum += pe;
            pv[e] = pe;
        }
        short4 ph;
        ph.x = f2bf(pv[0]); ph.y = f2bf(pv[1]); ph.z = f2bf(pv[2]); ph.w = f2bf(pv[3]);
        *(short4*)(smem + P_OFF + ((t & 1) << 13) + prow*256
                   + (((pc >> 1) ^ (prow & 7)) << 4) + ((pc & 1) << 3)) = ph;
    };

    auto ITER = [&](int t, i32x4& av, f32x4& fv, bf16x8* bcur, bf16x8* bnext) {
        if (t + 1 < TSTEPS) LOADB(t + 1, bnext);     // B(t+1) in flight across the step
        if (t + 1 < TSTEPS) EXPP(t + 1, av, fv);     // exp overlaps MFMA pipe
        if (t + 3 < TSTEPS) LOADA(t + 3, av, fv);    // adj/fd 2-step lead
        const int slot = (t & 1) << 13;
        bf16x8 af0 = *(const bf16x8*)(smem + P_OFF + slot + lr*256
                                      + (((kt*4 + lg) ^ (lr & 7)) << 4));
        bf16x8 af1 = *(const bf16x8*)(smem + P_OFF + slot + (16 + lr)*256
                                      + (((kt*4 + lg) ^ (lr & 7)) << 4));
        #pragma unroll
        for (int nt = 0; nt < 4; ++nt) {
            acc[0][nt] = __builtin_amdgcn_mfma_f32_16x16x32_bf16(af0, bcur[nt], acc[0][nt], 0, 0, 0);
            acc[1][nt] = __builtin_amdgcn_mfma_f32_16x16x32_bf16(af1, bcur[nt], acc[1][nt], 0, 0, 0);
        }
        __builtin_amdgcn_sched_barrier(0);
        asm volatile("s_waitcnt lgkmcnt(0)" ::: "memory");
        __builtin_amdgcn_s_barrier();
        __builtin_amdgcn_sched_barrier(0);
    };

    // prologue
    i32x4 aA, aB; f32x4 fA, fB;
    bf16x8 bA[4], bB[4];
    LOADA(0, aA, fA);
    LOADB(0, bA);
    LOADA(1, aB, fB);
    EXPP(0, aA, fA);          // writes P slot 0
    LOADA(2, aA, fA);
    __builtin_amdgcn_sched_barrier(0);
    asm volatile("s_waitcnt lgkmcnt(0)" ::: "memory");
    __builtin_amdgcn_s_barrier();
    __builtin_amdgcn_sched_barrier(0);

    for (int t2 = 0; t2 < TSTEPS; t2 += 2) {
        ITER(t2,     aB, fB, bA, bB);
        ITER(t2 + 1, aA, fA, bB, bA);
    }

    // ---- epilogue: row sums, kt-tree reduction, elu, coalesced store ----
    #pragma unroll
    for (int m = 1; m < 32; m <<= 1) lsum += __shfl_xor(lsum, m);
    if ((l & 31) == 0) ls[prow] = lsum;
    __syncthreads();

    float* red0 = (float*)(smem + RED0_OFF);
    float* red1 = (float*)(smem + RED1_OFF);
    if (kt >= 2) {
        float* dst = (kt == 2) ? red0 : red1;
        #pragma unroll
        for (int rg = 0; rg < 2; ++rg)
            #pragma unroll
            for (int nt = 0; nt < 4; ++nt)
                #pragma unroll
                for (int r = 0; r < 4; ++r)
                    dst[(rg*16 + lg*4 + r)*260 + fq*64 + nt*16 + lr] = acc[rg][nt][r];
    }
    __syncthreads();
    if (kt < 2) {
        const float* srcp = (kt == 0) ? red0 : red1;
        #pragma unroll
        for (int rg = 0; rg < 2; ++rg)
            #pragma unroll
            for (int nt = 0; nt < 4; ++nt)
                #pragma unroll
                for (int r = 0; r < 4; ++r)
                    acc[rg][nt][r] += srcp[(rg*16 + lg*4 + r)*260 + fq*64 + nt*16 + lr];
    }
    __syncthreads();
    if (kt == 1) {
        #pragma unroll
        for (int rg = 0; rg < 2; ++rg)
            #pragma unroll
            for (int nt = 0; nt < 4; ++nt)
                #pragma unroll
                for (int r = 0; r < 4; ++r)
                    red0[(rg*16 + lg*4 + r)*260 + fq*64 + nt*16 + lr] = acc[rg][nt][r];
    }
    __syncthreads();
    if (kt == 0) {
        #pragma unroll
        for (int rg = 0; rg < 2; ++rg)
            #pragma unroll
            for (int nt = 0; nt < 4; ++nt)
                #pragma unroll
                for (int r = 0; r < 4; ++r) {
                    int row = rg*16 + lg*4 + r;
                    int fcol = fq*64 + nt*16 + lr;
                    float v = acc[rg][nt][r] + red0[row*260 + fcol];
                    float lv = ls[row];
                    float rv = lv > 0.f ? 1.f / lv : 0.f;
                    v *= rv;
                    red1[row*260 + fcol] = v > 0.f ? v : expm1f(v);
                }
    }
    __syncthreads();
    {
        const int row = tid >> 5, f8 = (tid & 31) * 8;
        float4 v0 = *(const float4*)&red1[row*260 + f8];
        float4 v1 = *(const float4*)&red1[row*260 + f8 + 4];
        float* op = out + (size_t)(b*NN + i0 + row)*NF + f8;
        *(float4*)op       = v0;
        *(float4*)(op + 4) = v1;
    }
}

extern "C" void kernel_launch(void* const* d_in, const int* in_sizes, int n_in,
                              void* d_out, int out_size, void* d_ws, size_t ws_size,
                              hipStream_t stream) {
    const float* x   = (const float*)d_in[0];
    const int*   adj = (const int*)d_in[1];
    const float* W   = (const float*)d_in[2];
    const float* a   = (const float*)d_in[3];
    float* out = (float*)d_out;
    char* ws = (char*)d_ws;

    short* WT       = (short*)(ws);                   // 128 KB
    short* hT       = (short*)(ws + 0x20000);         // 4 MB
    float* fsrc     = (float*)(ws + 0x420000);        // 32 KB
    float* fdst     = (float*)(ws + 0x428000);        // 32 KB
    unsigned* maxfd = (unsigned*)(ws + 0x430000);     // 16 B
    short* xb       = (short*)(ws + 0x440000);        // 4 MB

    prep_kernel<<<1024, 256, 0, stream>>>(x, W, WT, xb, maxfd);
    h_kernel<<<(NB*NN)/16, 256, 0, stream>>>(xb, WT, a, hT, fsrc, fdst, maxfd);
    gat_fused<<<NB*(NN/32), 1024, 0, stream>>>(hT, adj, fsrc, fdst, maxfd, out);
}